// Round 2
// baseline (273.988 us; speedup 1.0000x reference)
//
#include <hip/hip_runtime.h>

// Fused morphological opening (22x22 flat SE), 8x3x1024x1024 f32, one kernel.
// opening = dilate(erode(x)); separable. Per 64x64 output tile:
//   P0 : colmin streamed global->regs->LDS   (B: 86 rows x stride 116)
//   P12: rowmin -> eroded (+ -inf border override) -> rowmax, ALL IN REGS,
//        single LDS read pass + single LDS write pass (f4 I/O)
//   P3 : colmax -> coalesced global store
// v3: 512-thread blocks (8 waves). LDS 39.9K caps blocks at 4/CU; with
// 256-thr blocks that was 16 waves/CU (50% occupancy) and the kernel is
// latency-bound (22-long dependent min/max chains, VALUBusy 48%). 8 waves/
// block -> 32 waves/CU potential; per-thread chunk sizes halved. VGPR must
// stay <=64 for 8 waves/SIMD: __launch_bounds__(512,8) pins the allocator.
// EVERY phase is balanced per WAVE INDEX (waves map one-per-SIMD):
//   P0 : 8 waves = 4 row-chunks (COUT=22, last base clamped to 64 -> benign
//        duplicate rows 64/65) x 2 col-halves; 54 lanes = consecutive cols
//   P12: 510 thr = 85 rows x 6 overlapping chunks (COUT=12, c0=12ch, last
//        clamped to 52); reads B cols [c0,c0+56), erodes 33, dilates 12,
//        writes [c0,c0+12). Overlaps recompute identical values.
//   P3 : 512 thr = 64 cols x 8 chunks of 8 rows
// Read-phase | barrier | write-phase ordering handles the in-place hazard.
// B stride 116: f4 row ops start-phase 29*o mod 8 (odd) -> spread across
// banks; scalar col ops (lanes=cols) 2-way aliased (free on CDNA4).
// Window for index i: [i-11, i+10]. Erosion pads +inf; eroded values outside
// the image are -inf for dilation (border override before rowmax).

#define HH 1024
#define WW 1024
#define KW 22
#define SB 116
#define PINF __builtin_inff()

template<bool IS_MIN>
__device__ __forceinline__ float vop(float a, float b) {
    return IS_MIN ? fminf(a, b) : fmaxf(a, b);
}

// van Herk / Gil-Werman, compile-time output count COUT (window KW=22).
// get(p): input at window-space p (output k's window = get(k..k+21)).
template<bool IS_MIN, int COUT, class Get, class Put>
__device__ __forceinline__ void vanherk(Get get, Put put) {
    constexpr int NIN = COUT + KW - 1;
    constexpr int NB = (NIN + KW - 1) / KW;
    const float ID = IS_MIN ? PINF : -PINF;
    float Sprev[KW];
    #pragma unroll
    for (int j = 0; j < NB; ++j) {
        const int base = KW * j;
        const int needed = (NIN - base) < KW ? (NIN - base) : KW;
        float v[KW];
        #pragma unroll
        for (int m = 0; m < KW; ++m)
            if (m < needed) v[m] = get(base + m);
        float p = ID;
        #pragma unroll
        for (int m = 0; m < KW; ++m) {
            if (m < needed) {
                p = vop<IS_MIN>(p, v[m]);
                const int k = base - (KW - 1) + m;
                if (k >= 0 && k < COUT) {
                    if (m == KW - 1) put(k, p);
                    else             put(k, vop<IS_MIN>(Sprev[m + 1], p));
                }
            }
        }
        if (j < NB - 1) {
            float s = ID;
            #pragma unroll
            for (int m = KW - 1; m >= 0; --m) {
                s = vop<IS_MIN>(s, v[m]);
                Sprev[m] = s;
            }
        }
    }
}

template<bool INTERIOR>
__device__ __forceinline__ void tile_body(const float* __restrict__ src,
                                          float* __restrict__ dst,
                                          int R, int C, float* B, int t) {
    const int w = t >> 6, slot = t & 63;

    // ---- P0: colmin, global -> B rows [0,86) x cols j in [0,108). ----
    // B row o = img row R-11+o; window = img rows [R-22+o, R-1+o].
    // wave = 2*rowchunk + colhalf; lanes 0..53 = consecutive cols.
    if (slot < 54) {
        const int ch = w >> 1;                    // 0..3
        const int j = (w & 1) * 54 + slot;
        const int base_o = (ch == 3) ? 64 : ch * 22;   // rows 64/65 duplicated
        int cj = C - 22 + j;
        bool colOK = true;
        if (!INTERIOR) {
            colOK = (unsigned)cj < WW;
            cj = cj < 0 ? 0 : (cj > WW - 1 ? WW - 1 : cj);
        }
        const float* col = src + cj;
        const int rbase = R - 22 + base_o;
        vanherk<true, 22>(
            [&](int p) {
                int r = rbase + p;
                if (INTERIOR) return col[r * WW];
                int rc = r < 0 ? 0 : (r > HH - 1 ? HH - 1 : r);
                float vv = col[rc * WW];
                return (colOK && (unsigned)r < HH) ? vv : PINF;
            },
            [&](int k, float vv) { B[(base_o + k) * SB + j] = vv; });
    }
    __syncthreads();

    // ---- P12: fused rowmin -> border override -> rowmax, in regs. ----
    // 85 rows (o = B row = img row R-11+o) x 6 chunks, COUT=12.
    // c0 = 12ch (last clamped to 52). rowmax[c] = max eroded [c, c+21];
    // eroded[e] = min B cols [e, e+21]. Chunk needs eroded [c0, c0+33)
    // hence B cols [c0, c0+54) -> read 14 f4 = [c0, c0+56) (<=108 at c0=52).
    // Reads all to regs, compute, barrier, then write: in-place safe.
    {
        const bool act = t < 510;
        const int ch = (772 * t) >> 16;           // t/85 for t<510
        const int o = t - 85 * ch;
        const int c0 = (ch == 5) ? 52 : 12 * ch;  // cols 52..59 duplicated
        const int g0 = c0 >> 2;
        float* Brow = B + o * SB;
        float in12[56];
        if (act) {
            #pragma unroll
            for (int i = 0; i < 14; ++i) {        // B cols [c0, c0+56)
                float4 x = ((const float4*)Brow)[g0 + i];
                in12[4 * i] = x.x; in12[4 * i + 1] = x.y;
                in12[4 * i + 2] = x.z; in12[4 * i + 3] = x.w;
            }
        }
        float rx[12];
        if (act) {
            float er[33];
            vanherk<true, 33>(
                [&](int p) { return in12[p]; },
                [&](int k, float vv) { er[k] = vv; });
            if (!INTERIOR) {
                // eroded positions outside the image are -inf for dilation
                const bool rOK = (unsigned)(R - 11 + o) < HH;
                #pragma unroll
                for (int k = 0; k < 33; ++k) {
                    const int cimg = C - 11 + c0 + k;
                    if (!rOK || (unsigned)cimg >= WW) er[k] = -PINF;
                }
            }
            vanherk<false, 12>(
                [&](int p) { return er[p]; },
                [&](int k, float vv) { rx[k] = vv; });
        }
        __syncthreads();                          // all reads before any write
        if (act) {
            #pragma unroll
            for (int i = 0; i < 3; ++i)           // rowmax cols [c0, c0+12)
                ((float4*)Brow)[g0 + i] =
                    make_float4(rx[4 * i], rx[4 * i + 1],
                                rx[4 * i + 2], rx[4 * i + 3]);
        }
        __syncthreads();
    }

    // ---- P3: colmax -> out. 64 cols x 8 chunks of 8 rows (all waves). ----
    // out row R+y: window = B rows [y, y+21] (rows 0..84 hold rowmax).
    {
        const int c = t & 63;
        const int y0 = (t >> 6) << 3;             // {0,8,...,56}
        float o8[8];
        vanherk<false, 8>(
            [&](int p) { return B[(y0 + p) * SB + c]; },
            [&](int k, float vv) { o8[k] = vv; });
        #pragma unroll
        for (int k = 0; k < 8; ++k)
            dst[(R + y0 + k) * WW + C + c] = o8[k];
    }
}

__global__ __launch_bounds__(512, 8) void fused_open(const float* __restrict__ in,
                                                     float* __restrict__ out) {
    __shared__ float B[86 * SB];                  // 39,904 B -> 4 blk/CU
    const int t = threadIdx.x;
    const int b = blockIdx.x;
    const int plane = b >> 8;
    const int by = (b >> 4) & 15;
    const int bx = b & 15;
    const int R = by * 64, C = bx * 64;
    const float* src = in + (size_t)plane * (HH * WW);
    float* dst = out + (size_t)plane * (HH * WW);

    if (by >= 1 && by <= 14 && bx >= 1 && bx <= 14)
        tile_body<true>(src, dst, R, C, B, t);
    else
        tile_body<false>(src, dst, R, C, B, t);
}

extern "C" void kernel_launch(void* const* d_in, const int* in_sizes, int n_in,
                              void* d_out, int out_size, void* d_ws, size_t ws_size,
                              hipStream_t stream) {
    const float* in = (const float*)d_in[0];
    float* out = (float*)d_out;
    (void)d_ws; (void)ws_size;
    fused_open<<<24 * 16 * 16, 512, 0, stream>>>(in, out);
}

// Round 3
// 199.867 us; speedup vs baseline: 1.3709x; 1.3709x over previous
//
#include <hip/hip_runtime.h>

// Fused morphological opening (22x22 flat SE), 8x3x1024x1024 f32, one kernel.
// opening = dilate(erode(x)); separable. Per 32x64 output tile:
//   P0 : colmin streamed global->regs->LDS   (B: 53 rows x stride 108)
//   P12: rowmin -> eroded (+ -inf border override) -> rowmax, ALL IN REGS,
//        single LDS read pass + single LDS write pass (f4 I/O)
//   P3 : colmax -> coalesced global store
// v4: tile 64x64 -> 32x64. LDS 39.9K allowed only 4 blk/CU (16 waves, 50%
// occ, VALUBusy 48% -> latency-bound on 22-long dependent min/max chains).
// B now 53x108x4B = 22.9K -> 7 blk/CU = 28 waves/CU (87.5%). 256 thr and
// ~52 VGPR working set UNCHANGED (v3's 512-thr/launch_bounds(512,8) squeeze
// clamped VGPR to 32 and rematerialized LDS reads inside the chains: 2.2x
// slower; never squeeze below the ~55-reg working set).
// __launch_bounds__(256,7) caps VGPR at 73 - safe above the measured 52.
// EVERY phase is balanced per WAVE INDEX (waves map one-per-SIMD;
// thread-range gating starves whole SIMDs across all resident blocks):
//   P0 : 54 lanes active per wave (consecutive cols -> coalesced);
//        wave = 2*rowchunk + colhalf; rowchunks base 0/26 (row 26 dup, benign)
//   P12: 53 lanes per wave; wave = col-chunk (COUT=16, c0=16w, EXACT tiling
//        of 64 cols, no overlap); lane = B row; reads B cols [c0,c0+60),
//        erodes 37, dilates 16, writes [c0,c0+16)
//   P3 : 64 lanes per wave; wave = row-chunk of 8 (COUT=8)
// Read-phase | barrier | write-phase ordering handles the in-place hazard.
// B stride 108: f4 row ops start dword-bank 12*o mod 32 (8 distinct starts
// per 8 lanes, each b128 covers 4 -> full 32-bank spread); scalar col ops
// (lanes=cols) consecutive banks. Window for index i: [i-11, i+10]. Erosion
// pads +inf; eroded values outside the image are -inf for dilation.

#define HH 1024
#define WW 1024
#define KW 22
#define SB 108
#define NR 53
#define PINF __builtin_inff()

template<bool IS_MIN>
__device__ __forceinline__ float vop(float a, float b) {
    return IS_MIN ? fminf(a, b) : fmaxf(a, b);
}

// van Herk / Gil-Werman, compile-time output count COUT (window KW=22).
// get(p): input at window-space p (output k's window = get(k..k+21)).
template<bool IS_MIN, int COUT, class Get, class Put>
__device__ __forceinline__ void vanherk(Get get, Put put) {
    constexpr int NIN = COUT + KW - 1;
    constexpr int NB = (NIN + KW - 1) / KW;
    const float ID = IS_MIN ? PINF : -PINF;
    float Sprev[KW];
    #pragma unroll
    for (int j = 0; j < NB; ++j) {
        const int base = KW * j;
        const int needed = (NIN - base) < KW ? (NIN - base) : KW;
        float v[KW];
        #pragma unroll
        for (int m = 0; m < KW; ++m)
            if (m < needed) v[m] = get(base + m);
        float p = ID;
        #pragma unroll
        for (int m = 0; m < KW; ++m) {
            if (m < needed) {
                p = vop<IS_MIN>(p, v[m]);
                const int k = base - (KW - 1) + m;
                if (k >= 0 && k < COUT) {
                    if (m == KW - 1) put(k, p);
                    else             put(k, vop<IS_MIN>(Sprev[m + 1], p));
                }
            }
        }
        if (j < NB - 1) {
            float s = ID;
            #pragma unroll
            for (int m = KW - 1; m >= 0; --m) {
                s = vop<IS_MIN>(s, v[m]);
                Sprev[m] = s;
            }
        }
    }
}

template<bool INTERIOR>
__device__ __forceinline__ void tile_body(const float* __restrict__ src,
                                          float* __restrict__ dst,
                                          int R, int C, float* B, int t) {
    const int w = t >> 6, slot = t & 63;

    // ---- P0: colmin, global -> B rows [0,53) x cols j in [0,108). ----
    // B row o = eroded img row R-11+o; window = img rows [R-22+o, R-1+o].
    // wave = 2*rowchunk + colhalf; lanes 0..53 = consecutive cols.
    if (slot < 54) {
        const int rowch = w >> 1;                 // 0..1
        const int j = (w & 1) * 54 + slot;
        const int base_o = rowch * 26;            // 0 or 26; row 26 duplicated
        int cj = C - 22 + j;
        bool colOK = true;
        if (!INTERIOR) {
            colOK = (unsigned)cj < WW;
            cj = cj < 0 ? 0 : (cj > WW - 1 ? WW - 1 : cj);
        }
        const float* col = src + cj;
        const int rbase = R - 22 + base_o;
        vanherk<true, 27>(
            [&](int p) {
                int r = rbase + p;
                if (INTERIOR) return col[r * WW];
                int rc = r < 0 ? 0 : (r > HH - 1 ? HH - 1 : r);
                float vv = col[rc * WW];
                return (colOK && (unsigned)r < HH) ? vv : PINF;
            },
            [&](int k, float vv) { B[(base_o + k) * SB + j] = vv; });
    }
    __syncthreads();

    // ---- P12: fused rowmin -> border override -> rowmax, in regs. ----
    // lane o = B row (53 active/wave); wave = col-chunk, COUT=16, c0=16w.
    // rowmax[c] = max eroded [c, c+21]; eroded[e] = min B cols [e, e+21].
    // Chunk needs eroded [c0, c0+37) hence B cols [c0, c0+58) -> 15 f4 =
    // [c0, c0+60) (= 108 exactly at c0=48). Read all -> compute -> barrier
    // -> write: in-place safe. Chunks tile cols exactly (4x16 = 64).
    {
        const int o = slot;
        const bool act = o < NR;
        const int c0 = 16 * w;
        const int g0 = 4 * w;
        float* Brow = B + o * SB;
        float in12[60];
        if (act) {
            #pragma unroll
            for (int i = 0; i < 15; ++i) {        // B cols [c0, c0+60)
                float4 x = ((const float4*)Brow)[g0 + i];
                in12[4 * i] = x.x; in12[4 * i + 1] = x.y;
                in12[4 * i + 2] = x.z; in12[4 * i + 3] = x.w;
            }
        }
        float rx[16];
        if (act) {
            float er[37];
            vanherk<true, 37>(
                [&](int p) { return in12[p]; },
                [&](int k, float vv) { er[k] = vv; });
            if (!INTERIOR) {
                // eroded positions outside the image are -inf for dilation
                const bool rOK = (unsigned)(R - 11 + o) < HH;
                #pragma unroll
                for (int k = 0; k < 37; ++k) {
                    const int cimg = C - 11 + c0 + k;
                    if (!rOK || (unsigned)cimg >= WW) er[k] = -PINF;
                }
            }
            vanherk<false, 16>(
                [&](int p) { return er[p]; },
                [&](int k, float vv) { rx[k] = vv; });
        }
        __syncthreads();                          // all reads before any write
        if (act) {
            #pragma unroll
            for (int i = 0; i < 4; ++i)           // rowmax cols [c0, c0+16)
                ((float4*)Brow)[g0 + i] =
                    make_float4(rx[4 * i], rx[4 * i + 1],
                                rx[4 * i + 2], rx[4 * i + 3]);
        }
        __syncthreads();
    }

    // ---- P3: colmax -> out. 64 cols x 4 chunks of 8 rows (all waves). ----
    // out row R+y: window = B rows [y, y+21] (rows 0..52 hold rowmax).
    {
        const int c = slot;
        const int y0 = w << 3;                    // {0,8,16,24}
        float o8[8];
        vanherk<false, 8>(
            [&](int p) { return B[(y0 + p) * SB + c]; },
            [&](int k, float vv) { o8[k] = vv; });
        #pragma unroll
        for (int k = 0; k < 8; ++k)
            dst[(R + y0 + k) * WW + C + c] = o8[k];
    }
}

__global__ __launch_bounds__(256, 7) void fused_open(const float* __restrict__ in,
                                                     float* __restrict__ out) {
    __shared__ float B[NR * SB];                  // 22,896 B -> 7 blk/CU
    const int t = threadIdx.x;
    const int b = blockIdx.x;
    const int plane = b >> 9;                     // 32 by x 16 bx = 512/plane
    const int by = (b >> 4) & 31;
    const int bx = b & 15;
    const int R = by * 32, C = bx * 64;
    const float* src = in + (size_t)plane * (HH * WW);
    float* dst = out + (size_t)plane * (HH * WW);

    if (by >= 1 && by <= 30 && bx >= 1 && bx <= 14)
        tile_body<true>(src, dst, R, C, B, t);
    else
        tile_body<false>(src, dst, R, C, B, t);
}

extern "C" void kernel_launch(void* const* d_in, const int* in_sizes, int n_in,
                              void* d_out, int out_size, void* d_ws, size_t ws_size,
                              hipStream_t stream) {
    const float* in = (const float*)d_in[0];
    float* out = (float*)d_out;
    (void)d_ws; (void)ws_size;
    fused_open<<<24 * 32 * 16, 256, 0, stream>>>(in, out);
}

// Round 5
// 188.182 us; speedup vs baseline: 1.4560x; 1.0621x over previous
//
#include <hip/hip_runtime.h>

// Fused morphological opening (22x22 flat SE), 8x3x1024x1024 f32, one kernel.
// opening = dilate(erode(x)); separable. Per 128x64 output tile (v5):
//   P0 : colmin streamed global->regs->LDS   (B: 149 rows x stride 108)
//   P12: rowmin -> eroded (+ -inf border override) -> rowmax, ALL IN REGS,
//        single LDS read pass + single LDS write pass (f4 I/O)
//   P3 : colmax -> coalesced global store
// v5: tile 64x64 -> 128x64, 512 threads, 2 blk/CU. Occupancy experiments
// (v3: 512thr/64-reg-cap -> remat disaster; v4: 32x64 tile -> +43% work for
// +13% delivered throughput) proved the waves<->work trade is flat; v2 was
// its optimum at 16 waves/CU. v5 keeps EXACTLY 16 waves/CU (2 blk x 8 waves,
// 4/SIMD) but amortizes the vertical halo over 128 rows: instr/elem
// ~50 -> ~46 (P0 19.3->17.7, P12 19.6->17.2, P3 11.3), barriers per elem
// halved, P0 load streams lengthened (59-deep). VGPR cap 128 via
// __launch_bounds__(512,4) leaves the ~52-reg working set untouched (the
// v3 trap was cap 64 -> compiler clamped to 32 and remat'd LDS reads).
// (v5 resubmit: R4 bench was an infra failure - "container failed twice" -
// with no counters; kernel re-audited: LDS 64,368B < 64K limit, barriers
// unconditional, all LDS/global accesses in bounds, duplicate writers
// byte-identical. Theory still untested, so rerun unchanged.)
// EVERY phase is balanced per WAVE INDEX (waves map one-per-SIMD;
// thread-range gating starves whole SIMDs across all resident blocks):
//   P0 : 8 waves = 4 rowchunks (COUT=38, bases {0,38,76,111}; overlap rows
//        recompute identical values) x 2 colhalves; 54 lanes = consec cols
//   P12: 56 lanes per wave; 448 units = 149 rows x 3 col-chunks (+1 dup);
//        unit: COUT=24, c0=20*chunk ([0,24)[20,44)[40,64), overlaps dup);
//        reads B cols [c0,c0+68), erodes 45, dilates 24, writes [c0,c0+24)
//   P3 : 64 lanes per wave; wave = row-chunk of 16 (y0=16w)
// Read-phase | barrier | write-phase ordering handles the in-place hazard.
// B stride 108: f4 row ops start dword-bank 12*o mod 32 (8 distinct starts,
// b128 covers 4 -> full 32-bank spread); scalar col ops (lanes=cols)
// consecutive banks (2-way, free). Window for index i: [i-11, i+10].
// Erosion pads +inf; eroded values outside the image are -inf for dilation.

#define HH 1024
#define WW 1024
#define KW 22
#define SB 108
#define NRB 149
#define PINF __builtin_inff()

template<bool IS_MIN>
__device__ __forceinline__ float vop(float a, float b) {
    return IS_MIN ? fminf(a, b) : fmaxf(a, b);
}

// van Herk / Gil-Werman, compile-time output count COUT (window KW=22).
// get(p): input at window-space p (output k's window = get(k..k+21)).
template<bool IS_MIN, int COUT, class Get, class Put>
__device__ __forceinline__ void vanherk(Get get, Put put) {
    constexpr int NIN = COUT + KW - 1;
    constexpr int NB = (NIN + KW - 1) / KW;
    const float ID = IS_MIN ? PINF : -PINF;
    float Sprev[KW];
    #pragma unroll
    for (int j = 0; j < NB; ++j) {
        const int base = KW * j;
        const int needed = (NIN - base) < KW ? (NIN - base) : KW;
        float v[KW];
        #pragma unroll
        for (int m = 0; m < KW; ++m)
            if (m < needed) v[m] = get(base + m);
        float p = ID;
        #pragma unroll
        for (int m = 0; m < KW; ++m) {
            if (m < needed) {
                p = vop<IS_MIN>(p, v[m]);
                const int k = base - (KW - 1) + m;
                if (k >= 0 && k < COUT) {
                    if (m == KW - 1) put(k, p);
                    else             put(k, vop<IS_MIN>(Sprev[m + 1], p));
                }
            }
        }
        if (j < NB - 1) {
            float s = ID;
            #pragma unroll
            for (int m = KW - 1; m >= 0; --m) {
                s = vop<IS_MIN>(s, v[m]);
                Sprev[m] = s;
            }
        }
    }
}

template<bool INTERIOR>
__device__ __forceinline__ void tile_body(const float* __restrict__ src,
                                          float* __restrict__ dst,
                                          int R, int C, float* B, int t) {
    const int w = t >> 6, slot = t & 63;

    // ---- P0: colmin, global -> B rows [0,149) x cols j in [0,108). ----
    // B row o = colmin at img row R-11+o; window = img rows [R-22+o, R-1+o].
    // wave = 2*rowchunk + colhalf; lanes 0..53 = consecutive cols.
    // rowchunk bases {0,38,76,111}: overlap rows recompute identical values.
    if (slot < 54) {
        const int rowch = w >> 1;                 // 0..3
        const int j = (w & 1) * 54 + slot;
        const int base_o = (rowch == 3) ? 111 : rowch * 38;
        int cj = C - 22 + j;
        bool colOK = true;
        if (!INTERIOR) {
            colOK = (unsigned)cj < WW;
            cj = cj < 0 ? 0 : (cj > WW - 1 ? WW - 1 : cj);
        }
        const float* col = src + cj;
        const int rbase = R - 22 + base_o;
        vanherk<true, 38>(
            [&](int p) {
                int r = rbase + p;
                if (INTERIOR) return col[r * WW];
                int rc = r < 0 ? 0 : (r > HH - 1 ? HH - 1 : r);
                float vv = col[rc * WW];
                return (colOK && (unsigned)r < HH) ? vv : PINF;
            },
            [&](int k, float vv) { B[(base_o + k) * SB + j] = vv; });
    }
    __syncthreads();

    // ---- P12: fused rowmin -> border override -> rowmax, in regs. ----
    // 448 units (56 per wave, uniform) = 149 rows x 3 chunks (+1 dup).
    // unit g: chunk = g/149, row o = g%149; COUT=24, c0=20*chunk
    // (chunks cover [0,24)[20,44)[40,64); overlaps write identical values).
    // rowmax[c] = max eroded [c, c+21]; eroded[e] = min B cols [e, e+21].
    // Chunk needs eroded [c0, c0+45) hence B cols [c0, c0+66) -> 17 f4 =
    // [c0, c0+68) (= 108 exactly at c0=40). Read all -> compute -> barrier
    // -> write: in-place safe.
    {
        const bool act = slot < 56;
        int g = w * 56 + slot;
        if (g > 446) g = 446;                     // wave7/slot55 dups unit 446
        const int chunk = (g >= 298) ? 2 : (g >= 149 ? 1 : 0);
        const int o = g - 149 * chunk;
        const int c0 = 20 * chunk;
        const int g0 = 5 * chunk;
        float* Brow = B + o * SB;
        float in12[68];
        if (act) {
            #pragma unroll
            for (int i = 0; i < 17; ++i) {        // B cols [c0, c0+68)
                float4 x = ((const float4*)Brow)[g0 + i];
                in12[4 * i] = x.x; in12[4 * i + 1] = x.y;
                in12[4 * i + 2] = x.z; in12[4 * i + 3] = x.w;
            }
        }
        float rx[24];
        if (act) {
            float er[45];
            vanherk<true, 45>(
                [&](int p) { return in12[p]; },
                [&](int k, float vv) { er[k] = vv; });
            if (!INTERIOR) {
                // eroded positions outside the image are -inf for dilation
                const bool rOK = (unsigned)(R - 11 + o) < HH;
                #pragma unroll
                for (int k = 0; k < 45; ++k) {
                    const int cimg = C - 11 + c0 + k;
                    if (!rOK || (unsigned)cimg >= WW) er[k] = -PINF;
                }
            }
            vanherk<false, 24>(
                [&](int p) { return er[p]; },
                [&](int k, float vv) { rx[k] = vv; });
        }
        __syncthreads();                          // all reads before any write
        if (act) {
            #pragma unroll
            for (int i = 0; i < 6; ++i)           // rowmax cols [c0, c0+24)
                ((float4*)Brow)[g0 + i] =
                    make_float4(rx[4 * i], rx[4 * i + 1],
                                rx[4 * i + 2], rx[4 * i + 3]);
        }
        __syncthreads();
    }

    // ---- P3: colmax -> out. 64 cols x 8 chunks of 16 rows (all waves). ----
    // out row R+y: window = B rows [y, y+21] (rows 0..148 hold rowmax).
    {
        const int c = slot;
        const int y0 = w << 4;                    // {0,16,...,112}
        float o16[16];
        vanherk<false, 16>(
            [&](int p) { return B[(y0 + p) * SB + c]; },
            [&](int k, float vv) { o16[k] = vv; });
        #pragma unroll
        for (int k = 0; k < 16; ++k)
            dst[(R + y0 + k) * WW + C + c] = o16[k];
    }
}

__global__ __launch_bounds__(512, 4) void fused_open(const float* __restrict__ in,
                                                     float* __restrict__ out) {
    __shared__ float B[NRB * SB];                 // 64,368 B -> 2 blk/CU
    const int t = threadIdx.x;
    const int b = blockIdx.x;
    const int plane = b >> 7;                     // 8 by x 16 bx = 128/plane
    const int by = (b >> 4) & 7;
    const int bx = b & 15;
    const int R = by * 128, C = bx * 64;
    const float* src = in + (size_t)plane * (HH * WW);
    float* dst = out + (size_t)plane * (HH * WW);

    // interior: P0 touches img rows [R-22, R+148], cols [C-22, C+85]
    if (by >= 1 && by <= 6 && bx >= 1 && bx <= 14)
        tile_body<true>(src, dst, R, C, B, t);
    else
        tile_body<false>(src, dst, R, C, B, t);
}

extern "C" void kernel_launch(void* const* d_in, const int* in_sizes, int n_in,
                              void* d_out, int out_size, void* d_ws, size_t ws_size,
                              hipStream_t stream) {
    const float* in = (const float*)d_in[0];
    float* out = (float*)d_out;
    (void)d_ws; (void)ws_size;
    fused_open<<<24 * 8 * 16, 512, 0, stream>>>(in, out);
}